// Round 16
// baseline (293.692 us; speedup 1.0000x reference)
//
#include <hip/hip_runtime.h>
#include <hip/hip_bf16.h>
#include <math.h>

#define B_    4
#define CIN_  64
#define COUT_ 64
#define DD    8
#define HH    48
#define WW    48
#define HW2   (HH * WW)        // 2304
#define NN    (DD * HH * WW)   // 18432
#define BN    (B_ * NN)        // 73728
#define KK    27
#define RS    116              // OM row stride in floats (conflict-spread)

typedef float f32x2 __attribute__((ext_vector_type(2)));
typedef float f32x4 __attribute__((ext_vector_type(4)));
typedef unsigned int u32x4 __attribute__((ext_vector_type(4)));
typedef __bf16 bf16x8 __attribute__((ext_vector_type(8)));
typedef __hip_bfloat16 bf16_t;

__device__ __forceinline__ float bflo(unsigned int u) {
  return __uint_as_float(u << 16);
}
__device__ __forceinline__ float bfhi(unsigned int u) {
  return __uint_as_float(u & 0xffff0000u);
}

// ---------------------------------------------------------------------------
// Fused init: zero-page + conv weights wB[k][ch(112)][cin] + deform weights
// wBd[k][cout][cin], all bf16. Grid covers 27*112*64 = 193536 exactly.
// ---------------------------------------------------------------------------
__global__ __launch_bounds__(256) void init_kernel(
    const float* __restrict__ w_off, const float* __restrict__ w_mask,
    const float* __restrict__ weight, bf16_t* __restrict__ wB,
    bf16_t* __restrict__ wBd, bf16_t* __restrict__ zp)
{
  const int o = blockIdx.x * 256 + threadIdx.x;
  {
    const int ci = o & 63;
    const int ch = (o >> 6) % 112;
    const int k  = o / (112 * 64);
    float v = 0.f;
    if (ch < 81)       v = w_off[((size_t)ch * CIN_ + ci) * KK + k];
    else if (ch < 108) v = w_mask[((size_t)(ch - 81) * CIN_ + ci) * KK + k];
    wB[o] = __float2bfloat16(v);
  }
  if (o < KK * CIN_ * COUT_) {
    const int ci = o & 63;
    const int co = (o >> 6) & 63;
    const int k  = o >> 12;
    wBd[o] = __float2bfloat16(weight[((size_t)co * CIN_ + ci) * KK + k]);
  }
  if (o < 128) zp[o] = __float2bfloat16(0.f);
}

// ---------------------------------------------------------------------------
// Transpose x[b][c][n] -> xTbf[b][n][c] in bf16.
// ---------------------------------------------------------------------------
__global__ __launch_bounds__(256) void transpose_x_kernel(
    const float* __restrict__ x, bf16_t* __restrict__ xTbf)
{
  const int tid = threadIdx.x;
  const int n0  = blockIdx.x * 64;
  const int b   = blockIdx.y;
  __shared__ float tile[64][65];

  for (int i = tid; i < 4096; i += 256) {
    const int c  = i >> 6;
    const int nl = i & 63;
    tile[c][nl] = x[((size_t)(b * CIN_ + c)) * NN + n0 + nl];
  }
  __syncthreads();
  for (int i = tid; i < 4096; i += 256) {
    const int nl = i >> 6;
    const int c  = i & 63;
    xTbf[((size_t)(b * NN + n0 + nl)) * CIN_ + c] = __float2bfloat16(tile[c][nl]);
  }
}

// ---------------------------------------------------------------------------
// FUSED kernel, 32-pos tiles, 2-way tap-split, DESC-shared trilinear setup:
//   Phase 1: conv — wave0 taps 0..13, wave1 taps 14..26; fp32 OM combine.
//   Phase 2: softmax over 27 logits (16 pos per wave).
//   Phase 3: deform — per tap, a setup pass (lane = pos*2+half) computes
//            each position's 8 corner {byte_row, wgt*m} ONCE into DESC;
//            the octet gather then reads descriptors (broadcast) + blends.
// Grid: 2304 blocks x 128 thr. LDS = 14848+9216+4096 = 28160 B.
// ---------------------------------------------------------------------------
__global__ __launch_bounds__(128) void fused_kernel(
    const bf16_t* __restrict__ xTbf, const bf16_t* __restrict__ wB,
    const float* __restrict__ b_off, const float* __restrict__ b_mask,
    const bf16_t* __restrict__ zp, const bf16_t* __restrict__ wBd,
    const float* __restrict__ bias, float* __restrict__ out)
{
  const int bid  = (blockIdx.x % 8) * 288 + blockIdx.x / 8;  // XCD swizzle (2304=8*288)
  const int tid  = threadIdx.x;
  const int wid  = tid >> 6;        // wave 0/1
  const int lane = tid & 63;
  const int lg   = lane >> 4;
  const int lr   = lane & 15;

  const int b    = bid / 576;       // one 32-pos tile per block
  const int rem  = bid % 576;
  const int z    = rem / 72;
  const int r2   = rem % 72;
  const int y0   = (r2 / 3) * 2;
  const int x0   = (r2 % 3) * 16;
  const int n0   = (z * HH + y0) * WW + x0;

  __shared__ float OM[32][RS];                   // 14,848 B (fp32 offsets+mask)
  __shared__ __align__(16) char SPu[9216];       // S[2][32][64] u16 / Pp[64][36] f32
  __shared__ __align__(16) unsigned int DESC[2][32][16];  // 4,096 B
  unsigned short* Sw  = (unsigned short*)SPu + wid * 2048;   // this wave's S tile
  unsigned int*   SwU = (unsigned int*)Sw;
  float*          Pp  = (float*)SPu;             // partial dacc (aliases S)

  const bf16_t* xb = xTbf + (size_t)b * NN * CIN_;

  // ================= Phase 1: conv, tap-split =================
  const int ck0 = wid ? 14 : 0;
  const int ck1 = wid ? 27 : 14;

  f32x4 acc[2][7];
#pragma unroll
  for (int mf = 0; mf < 2; ++mf)
#pragma unroll
    for (int nf = 0; nf < 7; ++nf) acc[mf][nf] = (f32x4){0.f, 0.f, 0.f, 0.f};

#pragma unroll 3
  for (int k = ck0; k < ck1; ++k) {
    const int kz = k / 9;
    const int kr = k - kz * 9;
    const int ky = kr / 3;
    const int kx = kr - ky * 3;

    bf16x8 afr[2][2];
    const int zz = z + kz - 1;
    const int xx = x0 + lr + kx - 1;
    const bool vzx = ((unsigned)zz < (unsigned)DD) & ((unsigned)xx < (unsigned)WW);
#pragma unroll
    for (int mf = 0; mf < 2; ++mf) {
      const int yy = y0 + mf + ky - 1;
      const bool v = vzx & ((unsigned)yy < (unsigned)HH);
      const bf16_t* ab = v ? (xb + (size_t)((zz * HH + yy) * WW + xx) * CIN_) : zp;
      afr[mf][0] = *(const bf16x8*)(ab + 8 * lg);
      afr[mf][1] = *(const bf16x8*)(ab + 32 + 8 * lg);
    }

    const bf16_t* wk = wB + (size_t)k * (112 * 64) + lr * 64 + 8 * lg;
    __builtin_amdgcn_s_setprio(1);
#pragma unroll
    for (int nf = 0; nf < 7; ++nf) {
      const bf16x8 b0 = *(const bf16x8*)(wk + nf * 1024);
      const bf16x8 b1 = *(const bf16x8*)(wk + nf * 1024 + 32);
      acc[0][nf] = __builtin_amdgcn_mfma_f32_16x16x32_bf16(afr[0][0], b0, acc[0][nf], 0, 0, 0);
      acc[1][nf] = __builtin_amdgcn_mfma_f32_16x16x32_bf16(afr[1][0], b0, acc[1][nf], 0, 0, 0);
      acc[0][nf] = __builtin_amdgcn_mfma_f32_16x16x32_bf16(afr[0][1], b1, acc[0][nf], 0, 0, 0);
      acc[1][nf] = __builtin_amdgcn_mfma_f32_16x16x32_bf16(afr[1][1], b1, acc[1][nf], 0, 0, 0);
    }
    __builtin_amdgcn_s_setprio(0);
  }

  // combine: wave0 writes (+bias), wave1 adds. slot = 4k+d / 4k+3 (logit).
  // C/D: pos = mf*16 + 4*lg + r; col ch = 16*nf+lr.
  if (wid == 0) {
#pragma unroll
    for (int nf = 0; nf < 7; ++nf) {
      const int ch = 16 * nf + lr;
      if (ch < 108) {
        const float bv   = (ch < 81) ? b_off[ch] : b_mask[ch - 81];
        const int   slot = (ch < 81) ? (4 * (ch / 3) + (ch % 3)) : (4 * (ch - 81) + 3);
#pragma unroll
        for (int mf = 0; mf < 2; ++mf)
#pragma unroll
          for (int r = 0; r < 4; ++r)
            OM[mf * 16 + 4 * lg + r][slot] = acc[mf][nf][r] + bv;
      }
    }
  }
  __syncthreads();
  if (wid == 1) {
#pragma unroll
    for (int nf = 0; nf < 7; ++nf) {
      const int ch = 16 * nf + lr;
      if (ch < 108) {
        const int slot = (ch < 81) ? (4 * (ch / 3) + (ch % 3)) : (4 * (ch - 81) + 3);
#pragma unroll
        for (int mf = 0; mf < 2; ++mf)
#pragma unroll
          for (int r = 0; r < 4; ++r)
            OM[mf * 16 + 4 * lg + r][slot] += acc[mf][nf][r];
      }
    }
  }
  __syncthreads();

  // ================= Phase 2: softmax over 27 logits =================
  if (lane < 16) {
    const int pos = wid * 16 + lane;
    float v[KK];
    float mx = -1e30f;
#pragma unroll
    for (int k = 0; k < KK; ++k) { v[k] = OM[pos][4 * k + 3]; mx = fmaxf(mx, v[k]); }
    float s = 0.f;
#pragma unroll
    for (int k = 0; k < KK; ++k) { v[k] = expf(v[k] - mx); s += v[k]; }
    const float inv = 1.f / s;
#pragma unroll
    for (int k = 0; k < KK; ++k) OM[pos][4 * k + 3] = v[k] * inv;
  }
  __syncthreads();

  // ================= Phase 3: deform, tap-split, DESC-shared setup =========
  const int p8 = lane >> 3;     // position within octet
  const int q  = lane & 7;      // channel octet
  const char* xqc = (const char*)xb + q * 16;

  // setup-lane role: position sp (0..31), corner half sh (0/1)
  const int sp = lane >> 1;
  const int sh = lane & 1;
  const float spz = (float)(z - 1);
  const float spy = (float)(y0 + (sp >> 4) - 1);
  const float spx = (float)(x0 + (sp & 15) - 1);

  const int dk0 = wid ? 14 : 0;
  const int dk1 = wid ? 27 : 14;

  f32x4 dacc[2][4];
#pragma unroll
  for (int mf = 0; mf < 2; ++mf)
#pragma unroll
    for (int nf = 0; nf < 4; ++nf) dacc[mf][nf] = (f32x4){0.f, 0.f, 0.f, 0.f};

#pragma unroll 2
  for (int k = dk0; k < dk1; ++k) {
    const int kz = k / 9;
    const int kr = k - kz * 9;
    const int ky = kr / 3;
    const int kx = kr - ky * 3;

    // ---- setup: each lane computes 4 corners {byte_row, wgt*m} for pos sp --
    {
      const f32x4 om = *(const f32x4*)(&OM[sp][4 * k]);
      const float pz = spz + (float)kz + om.x;
      const float py = spy + (float)ky + om.y;
      const float px = spx + (float)kx + om.z;
      const float m  = om.w;

      const float zf = floorf(pz); const float fz = pz - zf; const int z0 = (int)zf;
      const float yf = floorf(py); const float fy = py - yf; const int y0i = (int)yf;
      const float xf = floorf(px); const float fx = px - xf; const int xi0 = (int)xf;

      const float wz0 = ((unsigned)z0        < DD) ? (1.f - fz) : 0.f;
      const float wz1 = ((unsigned)(z0 + 1)  < DD) ? fz         : 0.f;
      const float wy0 = ((unsigned)y0i       < HH) ? (1.f - fy) : 0.f;
      const float wy1 = ((unsigned)(y0i + 1) < HH) ? fy         : 0.f;
      const float wx0 = ((unsigned)xi0       < WW) ? (1.f - fx) : 0.f;
      const float wx1 = ((unsigned)(xi0 + 1) < WW) ? fx         : 0.f;

      const int z0c = min(max(z0, 0),      DD - 1);
      const int z1c = min(max(z0 + 1, 0),  DD - 1);
      const int y0c = min(max(y0i, 0),     HH - 1);
      const int y1c = min(max(y0i + 1, 0), HH - 1);
      const int x0c = min(max(xi0, 0),     WW - 1);
      const int x1c = min(max(xi0 + 1, 0), WW - 1);

      const int   zcs = sh ? z1c : z0c;
      const float wzs = (sh ? wz1 : wz0) * m;
      const int   rzb = zcs * HH;

      unsigned int dw[8];
#pragma unroll
      for (int cc = 0; cc < 4; ++cc) {
        const int cy = cc >> 1, cx = cc & 1;
        const int row = (rzb + (cy ? y1c : y0c)) * WW + (cx ? x1c : x0c);
        const float wg = wzs * (cy ? wy1 : wy0) * (cx ? wx1 : wx0);
        dw[2 * cc]     = (unsigned)(row << 7);   // byte offset (128 B/row)
        dw[2 * cc + 1] = __float_as_uint(wg);
      }
      unsigned int* dst = &DESC[wid][sp][sh * 8];
      *(u32x4*)(dst)     = (u32x4){dw[0], dw[1], dw[2], dw[3]};
      *(u32x4*)(dst + 4) = (u32x4){dw[4], dw[5], dw[6], dw[7]};
    }

    // ---- gather 8 positions x 64 channels per octet ----
#pragma unroll
    for (int oct = 0; oct < 4; ++oct) {
      const int j = oct * 8 + p8;
      const u32x4* dp = (const u32x4*)(&DESC[wid][j][0]);
      const u32x4 dA = dp[0], dB = dp[1], dC = dp[2], dD = dp[3];

      u32x4 cv[8];
      cv[0] = *(const u32x4*)(xqc + dA.x);
      cv[1] = *(const u32x4*)(xqc + dA.z);
      cv[2] = *(const u32x4*)(xqc + dB.x);
      cv[3] = *(const u32x4*)(xqc + dB.z);
      cv[4] = *(const u32x4*)(xqc + dC.x);
      cv[5] = *(const u32x4*)(xqc + dC.z);
      cv[6] = *(const u32x4*)(xqc + dD.x);
      cv[7] = *(const u32x4*)(xqc + dD.z);
      const float wgt[8] = {
        __uint_as_float(dA.y), __uint_as_float(dA.w),
        __uint_as_float(dB.y), __uint_as_float(dB.w),
        __uint_as_float(dC.y), __uint_as_float(dC.w),
        __uint_as_float(dD.y), __uint_as_float(dD.w)};

      f32x2 a01 = {0.f, 0.f}, a23 = {0.f, 0.f}, a45 = {0.f, 0.f}, a67 = {0.f, 0.f};
#pragma unroll
      for (int c = 0; c < 8; ++c) {
        const float w_ = wgt[c];
        a01 += (f32x2){bflo(cv[c].x), bfhi(cv[c].x)} * w_;
        a23 += (f32x2){bflo(cv[c].y), bfhi(cv[c].y)} * w_;
        a45 += (f32x2){bflo(cv[c].z), bfhi(cv[c].z)} * w_;
        a67 += (f32x2){bflo(cv[c].w), bfhi(cv[c].w)} * w_;
      }

      unsigned int d0, d1, d2, d3;
      asm("v_cvt_pk_bf16_f32 %0, %1, %2" : "=v"(d0) : "v"(a01.x), "v"(a01.y));
      asm("v_cvt_pk_bf16_f32 %0, %1, %2" : "=v"(d1) : "v"(a23.x), "v"(a23.y));
      asm("v_cvt_pk_bf16_f32 %0, %1, %2" : "=v"(d2) : "v"(a45.x), "v"(a45.y));
      asm("v_cvt_pk_bf16_f32 %0, %1, %2" : "=v"(d3) : "v"(a67.x), "v"(a67.y));
      const int slot = q ^ (j & 7);               // XOR-swizzle (T2)
      *(u32x4*)(SwU + j * 32 + slot * 4) = (u32x4){d0, d1, d2, d3};
    }

    // ---- S[32x64] * W_k[64x64] via MFMA (wave-private S, no barrier) ----
    bf16x8 afr2[2][2];
#pragma unroll
    for (int mf = 0; mf < 2; ++mf)
#pragma unroll
      for (int t2 = 0; t2 < 2; ++t2) {
        const int row  = 16 * mf + lr;
        const int slot = (t2 * 4 + lg) ^ (row & 7);
        afr2[mf][t2] = *(const bf16x8*)(Sw + row * 64 + slot * 8);
      }
    const bf16_t* wk = wBd + (size_t)k * 4096 + lr * 64 + 8 * lg;
    __builtin_amdgcn_s_setprio(1);
#pragma unroll
    for (int nf = 0; nf < 4; ++nf) {
      const bf16x8 wv0 = *(const bf16x8*)(wk + nf * 1024);
      const bf16x8 wv1 = *(const bf16x8*)(wk + nf * 1024 + 32);
      dacc[0][nf] = __builtin_amdgcn_mfma_f32_16x16x32_bf16(afr2[0][0], wv0, dacc[0][nf], 0, 0, 0);
      dacc[1][nf] = __builtin_amdgcn_mfma_f32_16x16x32_bf16(afr2[1][0], wv0, dacc[1][nf], 0, 0, 0);
      dacc[0][nf] = __builtin_amdgcn_mfma_f32_16x16x32_bf16(afr2[0][1], wv1, dacc[0][nf], 0, 0, 0);
      dacc[1][nf] = __builtin_amdgcn_mfma_f32_16x16x32_bf16(afr2[1][1], wv1, dacc[1][nf], 0, 0, 0);
    }
    __builtin_amdgcn_s_setprio(0);
  }

  // ---- combine partial dacc across waves (Pp reuses the dead S buffers) ----
  __syncthreads();                 // all S reads done; safe to clobber
  if (wid == 1) {
#pragma unroll
    for (int nf = 0; nf < 4; ++nf)
#pragma unroll
      for (int mf = 0; mf < 2; ++mf)
        *(f32x4*)(Pp + (16 * nf + lr) * 36 + 16 * mf + 4 * lg) = dacc[mf][nf];
  }
  __syncthreads();
  if (wid == 0) {
#pragma unroll
    for (int nf = 0; nf < 4; ++nf) {
      const float bv = bias[16 * nf + lr];
      float* op = out + ((size_t)(b * COUT_ + 16 * nf + lr)) * NN + n0 + 4 * lg;
#pragma unroll
      for (int mf = 0; mf < 2; ++mf) {
        const f32x4 p = *(const f32x4*)(Pp + (16 * nf + lr) * 36 + 16 * mf + 4 * lg);
        *(f32x4*)(op + mf * WW) = dacc[mf][nf] + p + bv;
      }
    }
  }
}

// ---------------------------------------------------------------------------
extern "C" void kernel_launch(void* const* d_in, const int* in_sizes, int n_in,
                              void* d_out, int out_size, void* d_ws, size_t ws_size,
                              hipStream_t stream)
{
  const float* x      = (const float*)d_in[0];
  const float* w_off  = (const float*)d_in[1];
  const float* b_off  = (const float*)d_in[2];
  const float* w_mask = (const float*)d_in[3];
  const float* b_mask = (const float*)d_in[4];
  const float* weight = (const float*)d_in[5];
  const float* bias   = (const float*)d_in[6];
  float* out = (float*)d_out;

  // Workspace (bytes):
  //   xTbf : BN*64 bf16      = 9,437,184   @ 0
  //   wB   : 27*112*64 bf16  =   387,072   @ 9,437,184
  //   wBd  : 27*64*64 bf16   =   221,184   @ 9,824,256
  //   zp   : 256             @ 10,045,440
  // total ~10.0 MB
  char* ws = (char*)d_ws;
  bf16_t* xTbf = (bf16_t*)ws;
  bf16_t* wB   = (bf16_t*)(ws + 9437184);
  bf16_t* wBd  = (bf16_t*)(ws + 9824256);
  bf16_t* zp   = (bf16_t*)(ws + 10045440);

  init_kernel<<<(KK * 112 * 64) / 256, 256, 0, stream>>>(w_off, w_mask, weight,
                                                         wB, wBd, zp);
  dim3 gtx(NN / 64, B_);
  transpose_x_kernel<<<gtx, 256, 0, stream>>>(x, xTbf);

  fused_kernel<<<2304, 128, 0, stream>>>(xTbf, wB, b_off, b_mask, zp, wBd,
                                         bias, out);
}

// Round 17
// 279.371 us; speedup vs baseline: 1.0513x; 1.0513x over previous
//
#include <hip/hip_runtime.h>
#include <hip/hip_bf16.h>
#include <math.h>

#define B_    4
#define CIN_  64
#define COUT_ 64
#define DD    8
#define HH    48
#define WW    48
#define HW2   (HH * WW)        // 2304
#define NN    (DD * HH * WW)   // 18432
#define BN    (B_ * NN)        // 73728
#define KK    27
#define RS    116              // OM row stride in floats (conflict-spread)

typedef float f32x2 __attribute__((ext_vector_type(2)));
typedef float f32x4 __attribute__((ext_vector_type(4)));
typedef unsigned int u32x4 __attribute__((ext_vector_type(4)));
typedef __bf16 bf16x8 __attribute__((ext_vector_type(8)));
typedef __hip_bfloat16 bf16_t;

__device__ __forceinline__ float bflo(unsigned int u) {
  return __uint_as_float(u << 16);
}
__device__ __forceinline__ float bfhi(unsigned int u) {
  return __uint_as_float(u & 0xffff0000u);
}

// ---------------------------------------------------------------------------
// Fused init: zero-page + conv weights wB[k][ch(112)][cin] + deform weights
// wBd[k][cout][cin], all bf16. Grid covers 27*112*64 = 193536 exactly.
// ---------------------------------------------------------------------------
__global__ __launch_bounds__(256) void init_kernel(
    const float* __restrict__ w_off, const float* __restrict__ w_mask,
    const float* __restrict__ weight, bf16_t* __restrict__ wB,
    bf16_t* __restrict__ wBd, bf16_t* __restrict__ zp)
{
  const int o = blockIdx.x * 256 + threadIdx.x;
  {
    const int ci = o & 63;
    const int ch = (o >> 6) % 112;
    const int k  = o / (112 * 64);
    float v = 0.f;
    if (ch < 81)       v = w_off[((size_t)ch * CIN_ + ci) * KK + k];
    else if (ch < 108) v = w_mask[((size_t)(ch - 81) * CIN_ + ci) * KK + k];
    wB[o] = __float2bfloat16(v);
  }
  if (o < KK * CIN_ * COUT_) {
    const int ci = o & 63;
    const int co = (o >> 6) & 63;
    const int k  = o >> 12;
    wBd[o] = __float2bfloat16(weight[((size_t)co * CIN_ + ci) * KK + k]);
  }
  if (o < 128) zp[o] = __float2bfloat16(0.f);
}

// ---------------------------------------------------------------------------
// Transpose x[b][c][n] -> xTbf[b][n][c] in bf16.
// ---------------------------------------------------------------------------
__global__ __launch_bounds__(256) void transpose_x_kernel(
    const float* __restrict__ x, bf16_t* __restrict__ xTbf)
{
  const int tid = threadIdx.x;
  const int n0  = blockIdx.x * 64;
  const int b   = blockIdx.y;
  __shared__ float tile[64][65];

  for (int i = tid; i < 4096; i += 256) {
    const int c  = i >> 6;
    const int nl = i & 63;
    tile[c][nl] = x[((size_t)(b * CIN_ + c)) * NN + n0 + nl];
  }
  __syncthreads();
  for (int i = tid; i < 4096; i += 256) {
    const int nl = i >> 6;
    const int c  = i & 63;
    xTbf[((size_t)(b * NN + n0 + nl)) * CIN_ + c] = __float2bfloat16(tile[c][nl]);
  }
}

// ---------------------------------------------------------------------------
// FUSED kernel, 32-pos tiles, intra-block TAP-SPLIT (2 waves):
//   Phase 1: conv — wave0 taps 0..13, wave1 taps 14..26, both all 32 pos x
//            112 ch; fp32 OM combine in LDS (wave0 writes +bias, wave1 adds).
//   Phase 2: softmax over 27 logits (16 pos per wave).
//   Phase 3: deform — wave w gathers+GEMMs its taps over all 4 octets;
//            partial dacc combined via LDS (reusing the dead S buffers).
// Grid: 2304 blocks x 128 thr = 4608 waves (18/CU). LDS 23.5 KB -> 6 blk/CU.
// ---------------------------------------------------------------------------
__global__ __launch_bounds__(128) void fused_kernel(
    const bf16_t* __restrict__ xTbf, const bf16_t* __restrict__ wB,
    const float* __restrict__ b_off, const float* __restrict__ b_mask,
    const bf16_t* __restrict__ zp, const bf16_t* __restrict__ wBd,
    const float* __restrict__ bias, float* __restrict__ out)
{
  const int bid  = (blockIdx.x % 8) * 288 + blockIdx.x / 8;  // XCD swizzle (2304=8*288)
  const int tid  = threadIdx.x;
  const int wid  = tid >> 6;        // wave 0/1
  const int lane = tid & 63;
  const int lg   = lane >> 4;
  const int lr   = lane & 15;

  const int b    = bid / 576;       // one 32-pos tile per block
  const int rem  = bid % 576;
  const int z    = rem / 72;
  const int r2   = rem % 72;
  const int y0   = (r2 / 3) * 2;
  const int x0   = (r2 % 3) * 16;
  const int n0   = (z * HH + y0) * WW + x0;

  __shared__ float OM[32][RS];                   // 14,848 B (fp32 offsets+mask)
  __shared__ __align__(16) char SPu[9216];       // S[2][32][64] u16  /  Pp[64][36] f32
  unsigned short* Sw  = (unsigned short*)SPu + wid * 2048;   // this wave's S tile
  unsigned int*   SwU = (unsigned int*)Sw;
  float*          Pp  = (float*)SPu;             // partial dacc (aliases S)

  const bf16_t* xb = xTbf + (size_t)b * NN * CIN_;

  // ================= Phase 1: conv, tap-split =================
  const int ck0 = wid ? 14 : 0;
  const int ck1 = wid ? 27 : 14;

  f32x4 acc[2][7];
#pragma unroll
  for (int mf = 0; mf < 2; ++mf)
#pragma unroll
    for (int nf = 0; nf < 7; ++nf) acc[mf][nf] = (f32x4){0.f, 0.f, 0.f, 0.f};

#pragma unroll 3
  for (int k = ck0; k < ck1; ++k) {
    const int kz = k / 9;
    const int kr = k - kz * 9;
    const int ky = kr / 3;
    const int kx = kr - ky * 3;

    bf16x8 afr[2][2];
    const int zz = z + kz - 1;
    const int xx = x0 + lr + kx - 1;
    const bool vzx = ((unsigned)zz < (unsigned)DD) & ((unsigned)xx < (unsigned)WW);
#pragma unroll
    for (int mf = 0; mf < 2; ++mf) {
      const int yy = y0 + mf + ky - 1;
      const bool v = vzx & ((unsigned)yy < (unsigned)HH);
      const bf16_t* ab = v ? (xb + (size_t)((zz * HH + yy) * WW + xx) * CIN_) : zp;
      afr[mf][0] = *(const bf16x8*)(ab + 8 * lg);
      afr[mf][1] = *(const bf16x8*)(ab + 32 + 8 * lg);
    }

    const bf16_t* wk = wB + (size_t)k * (112 * 64) + lr * 64 + 8 * lg;
#pragma unroll
    for (int nf = 0; nf < 7; ++nf) {
      const bf16x8 b0 = *(const bf16x8*)(wk + nf * 1024);
      const bf16x8 b1 = *(const bf16x8*)(wk + nf * 1024 + 32);
      acc[0][nf] = __builtin_amdgcn_mfma_f32_16x16x32_bf16(afr[0][0], b0, acc[0][nf], 0, 0, 0);
      acc[1][nf] = __builtin_amdgcn_mfma_f32_16x16x32_bf16(afr[1][0], b0, acc[1][nf], 0, 0, 0);
      acc[0][nf] = __builtin_amdgcn_mfma_f32_16x16x32_bf16(afr[0][1], b1, acc[0][nf], 0, 0, 0);
      acc[1][nf] = __builtin_amdgcn_mfma_f32_16x16x32_bf16(afr[1][1], b1, acc[1][nf], 0, 0, 0);
    }
  }

  // combine: wave0 writes (+bias), wave1 adds. slot = 4k+d / 4k+3 (logit).
  // C/D: pos = mf*16 + 4*lg + r; col ch = 16*nf+lr.
  if (wid == 0) {
#pragma unroll
    for (int nf = 0; nf < 7; ++nf) {
      const int ch = 16 * nf + lr;
      if (ch < 108) {
        const float bv   = (ch < 81) ? b_off[ch] : b_mask[ch - 81];
        const int   slot = (ch < 81) ? (4 * (ch / 3) + (ch % 3)) : (4 * (ch - 81) + 3);
#pragma unroll
        for (int mf = 0; mf < 2; ++mf)
#pragma unroll
          for (int r = 0; r < 4; ++r)
            OM[mf * 16 + 4 * lg + r][slot] = acc[mf][nf][r] + bv;
      }
    }
  }
  __syncthreads();
  if (wid == 1) {
#pragma unroll
    for (int nf = 0; nf < 7; ++nf) {
      const int ch = 16 * nf + lr;
      if (ch < 108) {
        const int slot = (ch < 81) ? (4 * (ch / 3) + (ch % 3)) : (4 * (ch - 81) + 3);
#pragma unroll
        for (int mf = 0; mf < 2; ++mf)
#pragma unroll
          for (int r = 0; r < 4; ++r)
            OM[mf * 16 + 4 * lg + r][slot] += acc[mf][nf][r];
      }
    }
  }
  __syncthreads();

  // ================= Phase 2: softmax over 27 logits =================
  if (lane < 16) {
    const int pos = wid * 16 + lane;
    float v[KK];
    float mx = -1e30f;
#pragma unroll
    for (int k = 0; k < KK; ++k) { v[k] = OM[pos][4 * k + 3]; mx = fmaxf(mx, v[k]); }
    float s = 0.f;
#pragma unroll
    for (int k = 0; k < KK; ++k) { v[k] = expf(v[k] - mx); s += v[k]; }
    const float inv = 1.f / s;
#pragma unroll
    for (int k = 0; k < KK; ++k) OM[pos][4 * k + 3] = v[k] * inv;
  }
  __syncthreads();

  // ================= Phase 3: deform, tap-split =================
  const int p8 = lane >> 3;     // position within octet
  const int q  = lane & 7;      // channel octet

  const unsigned short* xq = (const unsigned short*)xb + (q << 3);

  float pxb[4], pyb[4];
#pragma unroll
  for (int oct = 0; oct < 4; ++oct) {
    const int j  = oct * 8 + p8;
    pyb[oct] = (float)(y0 + (j >> 4) - 1);
    pxb[oct] = (float)(x0 + (j & 15) - 1);
  }
  const float pzb = (float)(z - 1);

  const int dk0 = wid ? 14 : 0;
  const int dkN = wid ? 13 : 14;

  f32x4 dacc[2][4];
#pragma unroll
  for (int mf = 0; mf < 2; ++mf)
#pragma unroll
    for (int nf = 0; nf < 4; ++nf) dacc[mf][nf] = (f32x4){0.f, 0.f, 0.f, 0.f};

#pragma unroll 2
  for (int t = 0; t < dkN; ++t) {
    const int k  = dk0 + t;
    const int kz = k / 9;
    const int kr = k - kz * 9;
    const int ky = kr / 3;
    const int kx = kr - ky * 3;
    const float kzf = (float)kz, kyf = (float)ky, kxf = (float)kx;

    // ---- gather 8 positions x 64 channels per octet ----
#pragma unroll
    for (int oct = 0; oct < 4; ++oct) {
      const int j = oct * 8 + p8;
      const f32x4 om = *(const f32x4*)(&OM[j][4 * k]);   // ds_read_b128

      const float pz = pzb + kzf + om.x;
      const float py = pyb[oct] + kyf + om.y;
      const float px = pxb[oct] + kxf + om.z;
      const float m  = om.w;

      const float zf = floorf(pz); const float fz = pz - zf; const int z0 = (int)zf;
      const float yf = floorf(py); const float fy = py - yf; const int y0i = (int)yf;
      const float xf = floorf(px); const float fx = px - xf; const int xi0 = (int)xf;

      const float wz0 = ((unsigned)z0        < DD) ? (1.f - fz) : 0.f;
      const float wz1 = ((unsigned)(z0 + 1)  < DD) ? fz         : 0.f;
      const float wy0 = ((unsigned)y0i       < HH) ? (1.f - fy) : 0.f;
      const float wy1 = ((unsigned)(y0i + 1) < HH) ? fy         : 0.f;
      const float wx0 = ((unsigned)xi0       < WW) ? (1.f - fx) : 0.f;
      const float wx1 = ((unsigned)(xi0 + 1) < WW) ? fx         : 0.f;

      const int z0c = min(max(z0, 0),      DD - 1);
      const int z1c = min(max(z0 + 1, 0),  DD - 1);
      const int y0c = min(max(y0i, 0),     HH - 1);
      const int y1c = min(max(y0i + 1, 0), HH - 1);
      const int x0c = min(max(xi0, 0),     WW - 1);
      const int x1c = min(max(xi0 + 1, 0), WW - 1);

      const int r00 = (z0c * HH + y0c) * WW;
      const int r01 = (z0c * HH + y1c) * WW;
      const int r10 = (z1c * HH + y0c) * WW;
      const int r11 = (z1c * HH + y1c) * WW;

      const int rows[8] = {r00 + x0c, r00 + x1c, r01 + x0c, r01 + x1c,
                           r10 + x0c, r10 + x1c, r11 + x0c, r11 + x1c};
      const float w00 = wz0 * wy0, w01 = wz0 * wy1;
      const float w10 = wz1 * wy0, w11 = wz1 * wy1;
      const float wgt[8] = {w00 * wx0, w00 * wx1, w01 * wx0, w01 * wx1,
                            w10 * wx0, w10 * wx1, w11 * wx0, w11 * wx1};

      u32x4 cv[8];
#pragma unroll
      for (int c = 0; c < 8; ++c)
        cv[c] = *(const u32x4*)(xq + ((size_t)rows[c] << 6));

      f32x2 a01 = {0.f, 0.f}, a23 = {0.f, 0.f}, a45 = {0.f, 0.f}, a67 = {0.f, 0.f};
#pragma unroll
      for (int c = 0; c < 8; ++c) {
        const float w_ = wgt[c];
        a01 += (f32x2){bflo(cv[c].x), bfhi(cv[c].x)} * w_;
        a23 += (f32x2){bflo(cv[c].y), bfhi(cv[c].y)} * w_;
        a45 += (f32x2){bflo(cv[c].z), bfhi(cv[c].z)} * w_;
        a67 += (f32x2){bflo(cv[c].w), bfhi(cv[c].w)} * w_;
      }

      a01 *= m; a23 *= m; a45 *= m; a67 *= m;
      unsigned int d0, d1, d2, d3;
      asm("v_cvt_pk_bf16_f32 %0, %1, %2" : "=v"(d0) : "v"(a01.x), "v"(a01.y));
      asm("v_cvt_pk_bf16_f32 %0, %1, %2" : "=v"(d1) : "v"(a23.x), "v"(a23.y));
      asm("v_cvt_pk_bf16_f32 %0, %1, %2" : "=v"(d2) : "v"(a45.x), "v"(a45.y));
      asm("v_cvt_pk_bf16_f32 %0, %1, %2" : "=v"(d3) : "v"(a67.x), "v"(a67.y));
      const int slot = q ^ (j & 7);               // XOR-swizzle (T2)
      *(u32x4*)(SwU + j * 32 + slot * 4) = (u32x4){d0, d1, d2, d3};
    }

    // ---- S[32x64] * W_k[64x64] via MFMA (wave-private S, no barrier) ----
    bf16x8 afr2[2][2];
#pragma unroll
    for (int mf = 0; mf < 2; ++mf)
#pragma unroll
      for (int t2 = 0; t2 < 2; ++t2) {
        const int row  = 16 * mf + lr;
        const int slot = (t2 * 4 + lg) ^ (row & 7);
        afr2[mf][t2] = *(const bf16x8*)(Sw + row * 64 + slot * 8);
      }
    const bf16_t* wk = wBd + (size_t)k * 4096 + lr * 64 + 8 * lg;
#pragma unroll
    for (int nf = 0; nf < 4; ++nf) {
      const bf16x8 wv0 = *(const bf16x8*)(wk + nf * 1024);
      const bf16x8 wv1 = *(const bf16x8*)(wk + nf * 1024 + 32);
      dacc[0][nf] = __builtin_amdgcn_mfma_f32_16x16x32_bf16(afr2[0][0], wv0, dacc[0][nf], 0, 0, 0);
      dacc[1][nf] = __builtin_amdgcn_mfma_f32_16x16x32_bf16(afr2[1][0], wv0, dacc[1][nf], 0, 0, 0);
      dacc[0][nf] = __builtin_amdgcn_mfma_f32_16x16x32_bf16(afr2[0][1], wv1, dacc[0][nf], 0, 0, 0);
      dacc[1][nf] = __builtin_amdgcn_mfma_f32_16x16x32_bf16(afr2[1][1], wv1, dacc[1][nf], 0, 0, 0);
    }
  }

  // ---- combine partial dacc across waves (Pp reuses the dead S buffers) ----
  __syncthreads();                 // all S reads done; safe to clobber
  if (wid == 1) {
#pragma unroll
    for (int nf = 0; nf < 4; ++nf)
#pragma unroll
      for (int mf = 0; mf < 2; ++mf)
        *(f32x4*)(Pp + (16 * nf + lr) * 36 + 16 * mf + 4 * lg) = dacc[mf][nf];
  }
  __syncthreads();
  if (wid == 0) {
#pragma unroll
    for (int nf = 0; nf < 4; ++nf) {
      const float bv = bias[16 * nf + lr];
      float* op = out + ((size_t)(b * COUT_ + 16 * nf + lr)) * NN + n0 + 4 * lg;
#pragma unroll
      for (int mf = 0; mf < 2; ++mf) {
        const f32x4 p = *(const f32x4*)(Pp + (16 * nf + lr) * 36 + 16 * mf + 4 * lg);
        *(f32x4*)(op + mf * WW) = dacc[mf][nf] + p + bv;
      }
    }
  }
}

// ---------------------------------------------------------------------------
extern "C" void kernel_launch(void* const* d_in, const int* in_sizes, int n_in,
                              void* d_out, int out_size, void* d_ws, size_t ws_size,
                              hipStream_t stream)
{
  const float* x      = (const float*)d_in[0];
  const float* w_off  = (const float*)d_in[1];
  const float* b_off  = (const float*)d_in[2];
  const float* w_mask = (const float*)d_in[3];
  const float* b_mask = (const float*)d_in[4];
  const float* weight = (const float*)d_in[5];
  const float* bias   = (const float*)d_in[6];
  float* out = (float*)d_out;

  // Workspace (bytes):
  //   xTbf : BN*64 bf16      = 9,437,184   @ 0
  //   wB   : 27*112*64 bf16  =   387,072   @ 9,437,184
  //   wBd  : 27*64*64 bf16   =   221,184   @ 9,824,256
  //   zp   : 256             @ 10,045,440
  // total ~10.0 MB
  char* ws = (char*)d_ws;
  bf16_t* xTbf = (bf16_t*)ws;
  bf16_t* wB   = (bf16_t*)(ws + 9437184);
  bf16_t* wBd  = (bf16_t*)(ws + 9824256);
  bf16_t* zp   = (bf16_t*)(ws + 10045440);

  init_kernel<<<(KK * 112 * 64) / 256, 256, 0, stream>>>(w_off, w_mask, weight,
                                                         wB, wBd, zp);
  dim3 gtx(NN / 64, B_);
  transpose_x_kernel<<<gtx, 256, 0, stream>>>(x, xTbf);

  fused_kernel<<<2304, 128, 0, stream>>>(xTbf, wB, b_off, b_mask, zp, wBd,
                                         bias, out);
}